// Round 2
// baseline (1085.826 us; speedup 1.0000x reference)
//
#include <hip/hip_runtime.h>
#include <stdint.h>

// Problem constants (Gemma2 attention, B=1). All global tensors are FLOAT32
// (per reference setup_inputs); MFMA compute is bf16 internally.
#define S_LEN 2048
#define HDIM  3584
#define NHEAD 16
#define NKVH  8
#define DHEAD 256
#define QD    (NHEAD * DHEAD)   // 4096
#define KD    (NKVH * DHEAD)    // 2048
#define WINDOW 1024
#define MASK_VAL (-1e9f)

typedef __bf16 bf16x8 __attribute__((ext_vector_type(8)));
typedef float  f32x4  __attribute__((ext_vector_type(4)));

__device__ __forceinline__ float bf2f(ushort u) {
    union { uint32_t i; float f; } v; v.i = ((uint32_t)u) << 16; return v.f;
}
__device__ __forceinline__ ushort f2bf(float f) {
    union { float f; uint32_t i; } v; v.f = f;
    uint32_t r = (v.i + 0x7FFF + ((v.i >> 16) & 1)) >> 16;  // RNE
    return (ushort)r;
}

// ---------------------------------------------------------------------------
// Stage a [128][32] tile into LDS as bf16, converting from f32 if needed.
// ---------------------------------------------------------------------------
template <typename T>
__device__ __forceinline__ void stage_tile(ushort* __restrict__ dst,
                                           const T* __restrict__ src,
                                           int r0, int K, int kt, int t)
{
    if constexpr (sizeof(T) == 4) {  // f32 source -> convert
#pragma unroll
        for (int i = 0; i < 4; i++) {
            int g = t + i * 256;            // 1024 groups of 4 elements
            int row = g >> 3, c = g & 7;
            float4 f = *(const float4*)((const float*)src + (size_t)(r0 + row) * K + kt + c * 4);
            ushort4 u;
            u.x = f2bf(f.x); u.y = f2bf(f.y); u.z = f2bf(f.z); u.w = f2bf(f.w);
            *(ushort4*)(dst + row * 32 + c * 4) = u;
        }
    } else {  // bf16 source -> copy
#pragma unroll
        for (int i = 0; i < 2; i++) {
            int g = t + i * 256;            // 512 groups of 8 elements
            int row = g >> 2, c = g & 3;
            *(uint4*)(dst + row * 32 + c * 8) =
                *(const uint4*)((const ushort*)src + (size_t)(r0 + row) * K + kt + c * 8);
        }
    }
}

// ---------------------------------------------------------------------------
// GEMM: C[M,N] = A[M,K] * B[N,K]^T. A/B f32 or bf16(ushort), C f32 or bf16.
// 128x128 tile, BK=32, 256 threads (4 waves, 2x2 of 64x64 per wave).
// ---------------------------------------------------------------------------
template <typename TA, typename TB, typename TC>
__global__ __launch_bounds__(256) void gemm_bt(const TA* __restrict__ A,
                                               const TB* __restrict__ B,
                                               TC* __restrict__ C,
                                               int M, int N, int K)
{
    __shared__ __align__(16) ushort As[128 * 32];
    __shared__ __align__(16) ushort Bs[128 * 32];

    const int t    = threadIdx.x;
    const int lane = t & 63;
    const int w    = t >> 6;
    const int l15  = lane & 15;
    const int quad = lane >> 4;
    const int m0   = blockIdx.y * 128;
    const int n0   = blockIdx.x * 128;
    const int wm   = (w >> 1) * 64;
    const int wn   = (w & 1) * 64;

    f32x4 acc[4][4] = {};

    for (int kt = 0; kt < K; kt += 32) {
        __syncthreads();
        stage_tile<TA>(As, A, m0, K, kt, t);
        stage_tile<TB>(Bs, B, n0, K, kt, t);
        __syncthreads();

        bf16x8 a[4], b[4];
#pragma unroll
        for (int mi = 0; mi < 4; mi++)
            a[mi] = *(const bf16x8*)(As + (wm + mi * 16 + l15) * 32 + quad * 8);
#pragma unroll
        for (int ni = 0; ni < 4; ni++)
            b[ni] = *(const bf16x8*)(Bs + (wn + ni * 16 + l15) * 32 + quad * 8);
#pragma unroll
        for (int mi = 0; mi < 4; mi++)
#pragma unroll
            for (int ni = 0; ni < 4; ni++)
                acc[mi][ni] = __builtin_amdgcn_mfma_f32_16x16x32_bf16(
                    a[mi], b[ni], acc[mi][ni], 0, 0, 0);
    }

    // C/D layout: col = lane&15, row = quad*4 + r
#pragma unroll
    for (int mi = 0; mi < 4; mi++)
#pragma unroll
        for (int ni = 0; ni < 4; ni++)
#pragma unroll
            for (int r = 0; r < 4; r++) {
                int row = m0 + wm + mi * 16 + quad * 4 + r;
                int col = n0 + wn + ni * 16 + l15;
                float val = acc[mi][ni][r];
                if constexpr (sizeof(TC) == 4)
                    C[(size_t)row * N + col] = val;
                else
                    C[(size_t)row * N + col] = f2bf(val);
            }
}

// ---------------------------------------------------------------------------
// RoPE in-place on [S, nh, 256] bf16; cos/sin are f32 (S,256).
// ---------------------------------------------------------------------------
__global__ void rope_kernel(ushort* __restrict__ x,
                            const float* __restrict__ cosb,
                            const float* __restrict__ sinb, int nh)
{
    int idx  = blockIdx.x * blockDim.x + threadIdx.x;
    int d    = idx & 127;
    int rest = idx >> 7;
    int h    = rest & (nh - 1);
    int s    = rest / nh;
    size_t base = ((size_t)s * nh + h) * DHEAD;
    float c  = cosb[s * DHEAD + d];
    float sn = sinb[s * DHEAD + d];
    float x1 = bf2f(x[base + d]);
    float x2 = bf2f(x[base + d + 128]);
    x[base + d]       = f2bf(x1 * c - x2 * sn);
    x[base + d + 128] = f2bf(x2 * c + x1 * sn);
}

// ---------------------------------------------------------------------------
// Transpose V [S][KD] -> Vt [KD][S] bf16, 64x64 LDS tiles.
// ---------------------------------------------------------------------------
__global__ __launch_bounds__(256) void vtrans_kernel(const ushort* __restrict__ v,
                                                     ushort* __restrict__ vt)
{
    __shared__ __align__(16) ushort tile[64][72];
    int s0 = blockIdx.x * 64, c0 = blockIdx.y * 64;
    int t  = threadIdx.x;
#pragma unroll
    for (int i = 0; i < 2; i++) {
        int cI = t + i * 256;
        int row = cI >> 3, c8 = cI & 7;
        *(uint4*)&tile[row][c8 * 8] =
            *(const uint4*)(v + (size_t)(s0 + row) * KD + c0 + c8 * 8);
    }
    __syncthreads();
#pragma unroll
    for (int i = 0; i < 2; i++) {
        int cI = t + i * 256;
        int crow = cI >> 3, s8 = cI & 7;
        ushort tmp[8];
#pragma unroll
        for (int j = 0; j < 8; j++) tmp[j] = tile[s8 * 8 + j][crow];
        *(uint4*)(vt + (size_t)(c0 + crow) * S_LEN + s0 + s8 * 8) = *(uint4*)tmp;
    }
}

// ---------------------------------------------------------------------------
// Flash attention, sliding window 1024, softcap 50, scaling 1/16.
// Block = (64 q-rows, 1 head); 4 waves, 16 q-rows each. K-tile = 64.
// ---------------------------------------------------------------------------
template <typename TO>
__global__ __launch_bounds__(256) void attn_kernel(const ushort* __restrict__ qr,
                                                   const ushort* __restrict__ kr,
                                                   const ushort* __restrict__ vt,
                                                   TO* __restrict__ out)
{
    __shared__ __align__(16) ushort Ks[64 * 256];   // 32KB
    __shared__ __align__(16) ushort Ps[4][16 * 64]; // 8KB

    const int t    = threadIdx.x;
    const int lane = t & 63;
    const int w    = t >> 6;
    const int l15  = lane & 15;
    const int quad = lane >> 4;
    const int q0   = blockIdx.x * 64;
    const int h    = blockIdx.y;
    const int kvh  = h >> 1;  // GROUPS = 2

    bf16x8 aQ[8];
    const ushort* qrow = qr + (size_t)(q0 + w * 16 + l15) * QD + h * DHEAD;
#pragma unroll
    for (int kk = 0; kk < 8; kk++)
        aQ[kk] = *(const bf16x8*)(qrow + kk * 32 + quad * 8);

    f32x4 oacc[16] = {};
    float m_i[4], l_i[4];
#pragma unroll
    for (int r = 0; r < 4; r++) { m_i[r] = -1e30f; l_i[r] = 0.f; }

    int km = q0 - (WINDOW - 1);
    if (km < 0) km = 0;
    km &= ~63;

    for (int kb = km; kb < q0 + 64; kb += 64) {
        __syncthreads();
#pragma unroll
        for (int i = 0; i < 8; i++) {
            int cI = t + i * 256;
            int row = cI >> 5, c = cI & 31;
            ((uint4*)Ks)[cI] =
                *(const uint4*)(kr + (size_t)(kb + row) * KD + kvh * DHEAD + c * 8);
        }
        __syncthreads();

        f32x4 sc[4] = {};
#pragma unroll
        for (int ni = 0; ni < 4; ni++)
#pragma unroll
            for (int kk = 0; kk < 8; kk++) {
                bf16x8 bk = *(const bf16x8*)(Ks + (ni * 16 + l15) * 256 + kk * 32 + quad * 8);
                sc[ni] = __builtin_amdgcn_mfma_f32_16x16x32_bf16(aQ[kk], bk, sc[ni], 0, 0, 0);
            }

        float p[4][4];
        float mt[4] = { -1e30f, -1e30f, -1e30f, -1e30f };
#pragma unroll
        for (int ni = 0; ni < 4; ni++)
#pragma unroll
            for (int r = 0; r < 4; r++) {
                int qi = q0 + w * 16 + quad * 4 + r;
                int ki = kb + ni * 16 + l15;
                float x = sc[ni][r] * 0.0625f;          // SCALING = 1/16
                float e = __expf(x * 0.04f);            // tanh(x/50) via exp(2x/50)
                x = 50.f * (e - 1.f) / (e + 1.f);
                bool ok = (ki <= qi) && (qi - ki < WINDOW);
                x = ok ? x : MASK_VAL;
                p[ni][r] = x;
                mt[r] = fmaxf(mt[r], x);
            }
#pragma unroll
        for (int r = 0; r < 4; r++)
#pragma unroll
            for (int off = 1; off < 16; off <<= 1)
                mt[r] = fmaxf(mt[r], __shfl_xor(mt[r], off));

        float alpha[4], rs[4];
#pragma unroll
        for (int r = 0; r < 4; r++) {
            float mn = fmaxf(m_i[r], mt[r]);
            alpha[r] = __expf(m_i[r] - mn);
            m_i[r] = mn;
            rs[r] = 0.f;
        }
#pragma unroll
        for (int ni = 0; ni < 4; ni++)
#pragma unroll
            for (int r = 0; r < 4; r++) {
                float pe = __expf(p[ni][r] - m_i[r]);
                rs[r] += pe;
                Ps[w][(quad * 4 + r) * 64 + ni * 16 + l15] = f2bf(pe);
            }
#pragma unroll
        for (int r = 0; r < 4; r++) {
#pragma unroll
            for (int off = 1; off < 16; off <<= 1)
                rs[r] += __shfl_xor(rs[r], off);
            l_i[r] = l_i[r] * alpha[r] + rs[r];
        }
#pragma unroll
        for (int nd = 0; nd < 16; nd++)
#pragma unroll
            for (int r = 0; r < 4; r++)
                oacc[nd][r] *= alpha[r];

        __syncthreads();  // order P stores before vector re-reads

        bf16x8 aP[2];
#pragma unroll
        for (int kk = 0; kk < 2; kk++)
            aP[kk] = *(const bf16x8*)(&Ps[w][l15 * 64 + kk * 32 + quad * 8]);
#pragma unroll
        for (int nd = 0; nd < 16; nd++)
#pragma unroll
            for (int kk = 0; kk < 2; kk++) {
                bf16x8 bv = *(const bf16x8*)(vt +
                    (size_t)(kvh * DHEAD + nd * 16 + l15) * S_LEN + kb + kk * 32 + quad * 8);
                oacc[nd] = __builtin_amdgcn_mfma_f32_16x16x32_bf16(aP[kk], bv, oacc[nd], 0, 0, 0);
            }
    }

#pragma unroll
    for (int nd = 0; nd < 16; nd++)
#pragma unroll
        for (int r = 0; r < 4; r++) {
            int qi = q0 + w * 16 + quad * 4 + r;
            int d  = nd * 16 + l15;
            float val = oacc[nd][r] / l_i[r];
            if constexpr (sizeof(TO) == 4)
                out[(size_t)qi * QD + h * DHEAD + d] = val;
            else
                out[(size_t)qi * QD + h * DHEAD + d] = f2bf(val);
        }
}

// ---------------------------------------------------------------------------
extern "C" void kernel_launch(void* const* d_in, const int* in_sizes, int n_in,
                              void* d_out, int out_size, void* d_ws, size_t ws_size,
                              hipStream_t stream)
{
    const float* hidden = (const float*)d_in[0];  // [S, H]
    const float* cosb   = (const float*)d_in[1];  // [S, 256]
    const float* sinb   = (const float*)d_in[2];
    const float* wq     = (const float*)d_in[3];  // [4096, 3584]
    const float* wk     = (const float*)d_in[4];  // [2048, 3584]
    const float* wv     = (const float*)d_in[5];  // [2048, 3584]
    const float* wo     = (const float*)d_in[6];  // [3584, 4096]
    float* outp = (float*)d_out;

    // Workspace layout. attn buffer is f32 when ws allows (precision margin),
    // else bf16. Branch on ws_size is deterministic -> graph-safe.
    const size_t attnElems = (size_t)S_LEN * QD;
    const size_t bf16Elems = (size_t)S_LEN * (QD + 3 * KD);  // q,k,v,vt
    const bool attn_f32 = ws_size >= attnElems * 4 + bf16Elems * 2;

    char* ws = (char*)d_ws;
    float*  attnF = (float*)ws;
    ushort* attnH = (ushort*)ws;
    ushort* q  = (ushort*)(ws + (attn_f32 ? attnElems * 4 : attnElems * 2));
    ushort* k  = q + (size_t)S_LEN * QD;
    ushort* v  = k + (size_t)S_LEN * KD;
    ushort* vt = v + (size_t)S_LEN * KD;

    dim3 blk(256);
    gemm_bt<float, float, ushort><<<dim3(QD / 128, S_LEN / 128), blk, 0, stream>>>(hidden, wq, q, S_LEN, QD, HDIM);
    gemm_bt<float, float, ushort><<<dim3(KD / 128, S_LEN / 128), blk, 0, stream>>>(hidden, wk, k, S_LEN, KD, HDIM);
    gemm_bt<float, float, ushort><<<dim3(KD / 128, S_LEN / 128), blk, 0, stream>>>(hidden, wv, v, S_LEN, KD, HDIM);
    rope_kernel<<<(S_LEN * NHEAD * 128) / 256, blk, 0, stream>>>(q, cosb, sinb, NHEAD);
    rope_kernel<<<(S_LEN * NKVH * 128) / 256, blk, 0, stream>>>(k, cosb, sinb, NKVH);
    vtrans_kernel<<<dim3(S_LEN / 64, KD / 64), blk, 0, stream>>>(v, vt);
    if (attn_f32) {
        attn_kernel<float><<<dim3(S_LEN / 64, NHEAD), blk, 0, stream>>>(q, k, vt, attnF);
        gemm_bt<float, float, float><<<dim3(HDIM / 128, S_LEN / 128), blk, 0, stream>>>(attnF, wo, outp, S_LEN, HDIM, QD);
    } else {
        attn_kernel<ushort><<<dim3(S_LEN / 64, NHEAD), blk, 0, stream>>>(q, k, vt, attnH);
        gemm_bt<ushort, float, float><<<dim3(HDIM / 128, S_LEN / 128), blk, 0, stream>>>(attnH, wo, outp, S_LEN, HDIM, QD);
    }
}

// Round 3
// 852.841 us; speedup vs baseline: 1.2732x; 1.2732x over previous
//
#include <hip/hip_runtime.h>
#include <stdint.h>

// Problem constants (Gemma2 attention, B=1). Global tensors are FLOAT32;
// MFMA compute is bf16 internally.
#define S_LEN 2048
#define HDIM  3584
#define NHEAD 16
#define NKVH  8
#define DHEAD 256
#define QD    (NHEAD * DHEAD)   // 4096
#define KD    (NKVH * DHEAD)    // 2048
#define WINDOW 1024
#define MASK_VAL (-1e9f)

typedef __bf16 bf16x8 __attribute__((ext_vector_type(8)));
typedef float  f32x4  __attribute__((ext_vector_type(4)));

__device__ __forceinline__ float bf2f(ushort u) {
    union { uint32_t i; float f; } v; v.i = ((uint32_t)u) << 16; return v.f;
}
__device__ __forceinline__ ushort f2bf(float f) {
    union { float f; uint32_t i; } v; v.f = f;
    uint32_t r = (v.i + 0x7FFF + ((v.i >> 16) & 1)) >> 16;  // RNE
    return (ushort)r;
}

// ---------------------------------------------------------------------------
// f32 -> bf16 bulk convert. Each thread: 8 elements (2x float4 -> 16B store).
// ---------------------------------------------------------------------------
__global__ __launch_bounds__(256) void cvt_kernel(const float* __restrict__ src,
                                                  ushort* __restrict__ dst, int n8)
{
    int i = blockIdx.x * blockDim.x + threadIdx.x;
    if (i >= n8) return;
    float4 a = ((const float4*)src)[i * 2];
    float4 b = ((const float4*)src)[i * 2 + 1];
    ushort tmp[8];
    tmp[0] = f2bf(a.x); tmp[1] = f2bf(a.y); tmp[2] = f2bf(a.z); tmp[3] = f2bf(a.w);
    tmp[4] = f2bf(b.x); tmp[5] = f2bf(b.y); tmp[6] = f2bf(b.z); tmp[7] = f2bf(b.w);
    ((uint4*)dst)[i] = *(uint4*)tmp;
}

// ---------------------------------------------------------------------------
// Fast GEMM: C[M,N] = A[M,K]*B[N,K]^T, A/B bf16, global_load_lds staging.
// 128x128 tile, BK=32, 256 threads, 2x2 waves of 64x64.
// ---------------------------------------------------------------------------
template <typename TC>
__global__ __launch_bounds__(256) void gemm_async(const ushort* __restrict__ A,
                                                  const ushort* __restrict__ B,
                                                  TC* __restrict__ C,
                                                  int M, int N, int K)
{
    __shared__ __align__(16) ushort As[128 * 32];
    __shared__ __align__(16) ushort Bs[128 * 32];

    const int t    = threadIdx.x;
    const int lane = t & 63;
    const int w    = t >> 6;
    const int l15  = lane & 15;
    const int quad = lane >> 4;
    const int m0   = blockIdx.y * 128;
    const int n0   = blockIdx.x * 128;
    const int wm   = (w >> 1) * 64;
    const int wn   = (w & 1) * 64;

    const int srow = lane >> 2;        // 0..15 within a 16-row chunk
    const int scol = (lane & 3) * 8;   // element offset within 32

    f32x4 acc[4][4] = {};

    for (int kt = 0; kt < K; kt += 32) {
        __syncthreads();
#pragma unroll
        for (int j = 0; j < 2; j++) {
            const int rb = w * 32 + j * 16;
            const ushort* ga = A + (size_t)(m0 + rb + srow) * K + kt + scol;
            const ushort* gb = B + (size_t)(n0 + rb + srow) * K + kt + scol;
            __builtin_amdgcn_global_load_lds(
                (const __attribute__((address_space(1))) void*)ga,
                (__attribute__((address_space(3))) void*)(As + rb * 32), 16, 0, 0);
            __builtin_amdgcn_global_load_lds(
                (const __attribute__((address_space(1))) void*)gb,
                (__attribute__((address_space(3))) void*)(Bs + rb * 32), 16, 0, 0);
        }
        __syncthreads();

        bf16x8 a[4], b[4];
#pragma unroll
        for (int mi = 0; mi < 4; mi++)
            a[mi] = *(const bf16x8*)(As + (wm + mi * 16 + l15) * 32 + quad * 8);
#pragma unroll
        for (int ni = 0; ni < 4; ni++)
            b[ni] = *(const bf16x8*)(Bs + (wn + ni * 16 + l15) * 32 + quad * 8);
#pragma unroll
        for (int mi = 0; mi < 4; mi++)
#pragma unroll
            for (int ni = 0; ni < 4; ni++)
                acc[mi][ni] = __builtin_amdgcn_mfma_f32_16x16x32_bf16(
                    a[mi], b[ni], acc[mi][ni], 0, 0, 0);
    }

#pragma unroll
    for (int mi = 0; mi < 4; mi++)
#pragma unroll
        for (int ni = 0; ni < 4; ni++)
#pragma unroll
            for (int r = 0; r < 4; r++) {
                int row = m0 + wm + mi * 16 + quad * 4 + r;
                int col = n0 + wn + ni * 16 + l15;
                float val = acc[mi][ni][r];
                if constexpr (sizeof(TC) == 4) C[(size_t)row * N + col] = val;
                else                           C[(size_t)row * N + col] = f2bf(val);
            }
}

// ---------------------------------------------------------------------------
// Fallback GEMM (round-2 style): converts f32->bf16 during staging.
// ---------------------------------------------------------------------------
template <typename T>
__device__ __forceinline__ void stage_tile(ushort* __restrict__ dst,
                                           const T* __restrict__ src,
                                           int r0, int K, int kt, int t)
{
    if constexpr (sizeof(T) == 4) {
#pragma unroll
        for (int i = 0; i < 4; i++) {
            int g = t + i * 256;
            int row = g >> 3, c = g & 7;
            float4 f = *(const float4*)((const float*)src + (size_t)(r0 + row) * K + kt + c * 4);
            ushort4 u;
            u.x = f2bf(f.x); u.y = f2bf(f.y); u.z = f2bf(f.z); u.w = f2bf(f.w);
            *(ushort4*)(dst + row * 32 + c * 4) = u;
        }
    } else {
#pragma unroll
        for (int i = 0; i < 2; i++) {
            int g = t + i * 256;
            int row = g >> 2, c = g & 3;
            *(uint4*)(dst + row * 32 + c * 8) =
                *(const uint4*)((const ushort*)src + (size_t)(r0 + row) * K + kt + c * 8);
        }
    }
}

template <typename TA, typename TB, typename TC>
__global__ __launch_bounds__(256) void gemm_sync(const TA* __restrict__ A,
                                                 const TB* __restrict__ B,
                                                 TC* __restrict__ C,
                                                 int M, int N, int K)
{
    __shared__ __align__(16) ushort As[128 * 32];
    __shared__ __align__(16) ushort Bs[128 * 32];

    const int t    = threadIdx.x;
    const int lane = t & 63;
    const int w    = t >> 6;
    const int l15  = lane & 15;
    const int quad = lane >> 4;
    const int m0   = blockIdx.y * 128;
    const int n0   = blockIdx.x * 128;
    const int wm   = (w >> 1) * 64;
    const int wn   = (w & 1) * 64;

    f32x4 acc[4][4] = {};

    for (int kt = 0; kt < K; kt += 32) {
        __syncthreads();
        stage_tile<TA>(As, A, m0, K, kt, t);
        stage_tile<TB>(Bs, B, n0, K, kt, t);
        __syncthreads();

        bf16x8 a[4], b[4];
#pragma unroll
        for (int mi = 0; mi < 4; mi++)
            a[mi] = *(const bf16x8*)(As + (wm + mi * 16 + l15) * 32 + quad * 8);
#pragma unroll
        for (int ni = 0; ni < 4; ni++)
            b[ni] = *(const bf16x8*)(Bs + (wn + ni * 16 + l15) * 32 + quad * 8);
#pragma unroll
        for (int mi = 0; mi < 4; mi++)
#pragma unroll
            for (int ni = 0; ni < 4; ni++)
                acc[mi][ni] = __builtin_amdgcn_mfma_f32_16x16x32_bf16(
                    a[mi], b[ni], acc[mi][ni], 0, 0, 0);
    }

#pragma unroll
    for (int mi = 0; mi < 4; mi++)
#pragma unroll
        for (int ni = 0; ni < 4; ni++)
#pragma unroll
            for (int r = 0; r < 4; r++) {
                int row = m0 + wm + mi * 16 + quad * 4 + r;
                int col = n0 + wn + ni * 16 + l15;
                float val = acc[mi][ni][r];
                if constexpr (sizeof(TC) == 4) C[(size_t)row * N + col] = val;
                else                           C[(size_t)row * N + col] = f2bf(val);
            }
}

// ---------------------------------------------------------------------------
// RoPE in-place on [S, nh, 256] bf16; cos/sin f32 (S,256).
// ---------------------------------------------------------------------------
__global__ void rope_kernel(ushort* __restrict__ x,
                            const float* __restrict__ cosb,
                            const float* __restrict__ sinb, int nh)
{
    int idx  = blockIdx.x * blockDim.x + threadIdx.x;
    int d    = idx & 127;
    int rest = idx >> 7;
    int h    = rest & (nh - 1);
    int s    = rest / nh;
    size_t base = ((size_t)s * nh + h) * DHEAD;
    float c  = cosb[s * DHEAD + d];
    float sn = sinb[s * DHEAD + d];
    float x1 = bf2f(x[base + d]);
    float x2 = bf2f(x[base + d + 128]);
    x[base + d]       = f2bf(x1 * c - x2 * sn);
    x[base + d + 128] = f2bf(x2 * c + x1 * sn);
}

// ---------------------------------------------------------------------------
// Transpose V [S][KD] -> Vt [KD][S] bf16, 64x64 LDS tiles.
// ---------------------------------------------------------------------------
__global__ __launch_bounds__(256) void vtrans_kernel(const ushort* __restrict__ v,
                                                     ushort* __restrict__ vt)
{
    __shared__ __align__(16) ushort tile[64][72];
    int s0 = blockIdx.x * 64, c0 = blockIdx.y * 64;
    int t  = threadIdx.x;
#pragma unroll
    for (int i = 0; i < 2; i++) {
        int cI = t + i * 256;
        int row = cI >> 3, c8 = cI & 7;
        *(uint4*)&tile[row][c8 * 8] =
            *(const uint4*)(v + (size_t)(s0 + row) * KD + c0 + c8 * 8);
    }
    __syncthreads();
#pragma unroll
    for (int i = 0; i < 2; i++) {
        int cI = t + i * 256;
        int crow = cI >> 3, s8 = cI & 7;
        ushort tmp[8];
#pragma unroll
        for (int j = 0; j < 8; j++) tmp[j] = tile[s8 * 8 + j][crow];
        *(uint4*)(vt + (size_t)(c0 + crow) * S_LEN + s0 + s8 * 8) = *(uint4*)tmp;
    }
}

// ---------------------------------------------------------------------------
// Per-wave flash attention: one wave = one 16-row q-tile of one head.
// No block barriers. K/V fragments read direct from global (L2-resident).
// P transits per-wave LDS (C-layout -> A-layout) with a wave-local fence.
// ---------------------------------------------------------------------------
template <typename TO>
__global__ __launch_bounds__(256) void attn_kernel(const ushort* __restrict__ qr,
                                                   const ushort* __restrict__ kr,
                                                   const ushort* __restrict__ vt,
                                                   TO* __restrict__ out)
{
    __shared__ __align__(16) ushort Ps[4][16 * 64];  // per-wave 2KB

    const int t    = threadIdx.x;
    const int lane = t & 63;
    const int w    = t >> 6;
    const int l15  = lane & 15;
    const int quad = lane >> 4;
    const int qt   = blockIdx.x * 4 + w;   // q-tile index 0..127
    const int q0   = qt * 16;
    const int h    = blockIdx.y;
    const int kvh  = h >> 1;               // GROUPS = 2

    // Q fragments (A-layout): row l15, k-chunks kk*32 + quad*8
    bf16x8 aQ[8];
    const ushort* qrow = qr + (size_t)(q0 + l15) * QD + h * DHEAD;
#pragma unroll
    for (int kk = 0; kk < 8; kk++)
        aQ[kk] = *(const bf16x8*)(qrow + kk * 32 + quad * 8);

    f32x4 oacc[16] = {};
    float m_i[4], l_i[4];
#pragma unroll
    for (int r = 0; r < 4; r++) { m_i[r] = -1e30f; l_i[r] = 0.f; }

    int km = q0 - (WINDOW - 1);
    if (km < 0) km = 0;
    km &= ~63;

    for (int kb = km; kb < q0 + 16; kb += 64) {
        // ---- scores: S[16q][64k] ----
        f32x4 sc[4] = {};
        const ushort* kbase = kr + (size_t)(kb + l15) * KD + kvh * DHEAD;
#pragma unroll
        for (int ni = 0; ni < 4; ni++)
#pragma unroll
            for (int kk = 0; kk < 8; kk++) {
                bf16x8 bk = *(const bf16x8*)(kbase + (size_t)ni * 16 * KD + kk * 32 + quad * 8);
                sc[ni] = __builtin_amdgcn_mfma_f32_16x16x32_bf16(aQ[kk], bk, sc[ni], 0, 0, 0);
            }

        // ---- softcap + mask + online softmax ----
        float p[4][4];
        float mt[4] = { -1e30f, -1e30f, -1e30f, -1e30f };
#pragma unroll
        for (int ni = 0; ni < 4; ni++)
#pragma unroll
            for (int r = 0; r < 4; r++) {
                int qi = q0 + quad * 4 + r;
                int ki = kb + ni * 16 + l15;
                float x = sc[ni][r] * 0.0625f;          // SCALING = 1/16
                float e = __expf(x * 0.04f);            // tanh via exp(2x/50)
                x = 50.f * (e - 1.f) / (e + 1.f);
                bool ok = (ki <= qi) && (qi - ki < WINDOW);
                x = ok ? x : MASK_VAL;
                p[ni][r] = x;
                mt[r] = fmaxf(mt[r], x);
            }
#pragma unroll
        for (int r = 0; r < 4; r++)
#pragma unroll
            for (int off = 1; off < 16; off <<= 1)
                mt[r] = fmaxf(mt[r], __shfl_xor(mt[r], off));

        float alpha[4], rs[4];
#pragma unroll
        for (int r = 0; r < 4; r++) {
            float mn = fmaxf(m_i[r], mt[r]);
            alpha[r] = __expf(m_i[r] - mn);
            m_i[r] = mn;
            rs[r] = 0.f;
        }
#pragma unroll
        for (int ni = 0; ni < 4; ni++)
#pragma unroll
            for (int r = 0; r < 4; r++) {
                float pe = __expf(p[ni][r] - m_i[r]);
                rs[r] += pe;
                Ps[w][(quad * 4 + r) * 64 + ni * 16 + l15] = f2bf(pe);
            }
#pragma unroll
        for (int r = 0; r < 4; r++) {
#pragma unroll
            for (int off = 1; off < 16; off <<= 1)
                rs[r] += __shfl_xor(rs[r], off);
            l_i[r] = l_i[r] * alpha[r] + rs[r];
        }
#pragma unroll
        for (int nd = 0; nd < 16; nd++)
#pragma unroll
            for (int r = 0; r < 4; r++)
                oacc[nd][r] *= alpha[r];

        // wave-local fence: order P stores before A-frag re-reads
        __asm__ volatile("s_waitcnt lgkmcnt(0)" ::: "memory");

        // ---- PV: O[16q][256d] += P[16x64] * V-tile ----
        bf16x8 aP[2];
#pragma unroll
        for (int kk = 0; kk < 2; kk++)
            aP[kk] = *(const bf16x8*)(&Ps[w][l15 * 64 + kk * 32 + quad * 8]);
        const ushort* vbase = vt + (size_t)(kvh * DHEAD + l15) * S_LEN + kb;
#pragma unroll
        for (int nd = 0; nd < 16; nd++)
#pragma unroll
            for (int kk = 0; kk < 2; kk++) {
                bf16x8 bv = *(const bf16x8*)(vbase + (size_t)nd * 16 * S_LEN + kk * 32 + quad * 8);
                oacc[nd] = __builtin_amdgcn_mfma_f32_16x16x32_bf16(aP[kk], bv, oacc[nd], 0, 0, 0);
            }
    }

#pragma unroll
    for (int nd = 0; nd < 16; nd++)
#pragma unroll
        for (int r = 0; r < 4; r++) {
            int qi = q0 + quad * 4 + r;
            int d  = nd * 16 + l15;
            float val = oacc[nd][r] / l_i[r];
            if constexpr (sizeof(TO) == 4) out[(size_t)qi * QD + h * DHEAD + d] = val;
            else                           out[(size_t)qi * QD + h * DHEAD + d] = f2bf(val);
        }
}

// ---------------------------------------------------------------------------
extern "C" void kernel_launch(void* const* d_in, const int* in_sizes, int n_in,
                              void* d_out, int out_size, void* d_ws, size_t ws_size,
                              hipStream_t stream)
{
    const float* hidden = (const float*)d_in[0];  // [S, H]
    const float* cosb   = (const float*)d_in[1];  // [S, 256]
    const float* sinb   = (const float*)d_in[2];
    const float* wq     = (const float*)d_in[3];  // [4096, 3584]
    const float* wk     = (const float*)d_in[4];  // [2048, 3584]
    const float* wv     = (const float*)d_in[5];  // [2048, 3584]
    const float* wo     = (const float*)d_in[6];  // [3584, 4096]
    float* outp = (float*)d_out;

    const size_t nH  = (size_t)S_LEN * HDIM;   // hidden
    const size_t nWQ = (size_t)QD * HDIM;
    const size_t nWK = (size_t)KD * HDIM;
    const size_t nWO = (size_t)HDIM * QD;
    const size_t nQ  = (size_t)S_LEN * QD;
    const size_t nK  = (size_t)S_LEN * KD;
    // fast path: bf16 copies of hidden+weights, plus q/k/v/vt/attn (bf16)
    const size_t fastBytes = (nH + nWQ + 2 * nWK + nWO + nQ + 3 * nK + nQ) * 2;

    dim3 blk(256);

    if (ws_size >= fastBytes) {
        ushort* hb = (ushort*)d_ws;
        ushort* qb = hb + nH;
        ushort* kb = qb + nWQ;
        ushort* vb = kb + nWK;
        ushort* ob = vb + nWK;
        ushort* q  = ob + nWO;
        ushort* k  = q  + nQ;
        ushort* v  = k  + nK;
        ushort* vt = v  + nK;
        ushort* at = vt + nK;

        cvt_kernel<<<(int)(nH  / 8 / 256), blk, 0, stream>>>(hidden, hb, (int)(nH  / 8));
        cvt_kernel<<<(int)(nWQ / 8 / 256), blk, 0, stream>>>(wq,     qb, (int)(nWQ / 8));
        cvt_kernel<<<(int)(nWK / 8 / 256), blk, 0, stream>>>(wk,     kb, (int)(nWK / 8));
        cvt_kernel<<<(int)(nWK / 8 / 256), blk, 0, stream>>>(wv,     vb, (int)(nWK / 8));
        cvt_kernel<<<(int)(nWO / 8 / 256), blk, 0, stream>>>(wo,     ob, (int)(nWO / 8));

        gemm_async<ushort><<<dim3(QD / 128, S_LEN / 128), blk, 0, stream>>>(hb, qb, q, S_LEN, QD, HDIM);
        gemm_async<ushort><<<dim3(KD / 128, S_LEN / 128), blk, 0, stream>>>(hb, kb, k, S_LEN, KD, HDIM);
        gemm_async<ushort><<<dim3(KD / 128, S_LEN / 128), blk, 0, stream>>>(hb, vb, v, S_LEN, KD, HDIM);
        rope_kernel<<<(S_LEN * NHEAD * 128) / 256, blk, 0, stream>>>(q, cosb, sinb, NHEAD);
        rope_kernel<<<(S_LEN * NKVH * 128) / 256, blk, 0, stream>>>(k, cosb, sinb, NKVH);
        vtrans_kernel<<<dim3(S_LEN / 64, KD / 64), blk, 0, stream>>>(v, vt);
        attn_kernel<ushort><<<dim3(S_LEN / 64, NHEAD), blk, 0, stream>>>(q, k, vt, at);
        gemm_async<float><<<dim3(HDIM / 128, S_LEN / 128), blk, 0, stream>>>(at, ob, outp, S_LEN, HDIM, QD);
    } else {
        // fallback: convert-in-staging (round-2 structure, new attention)
        const size_t attnElems = nQ;
        const size_t bf16Elems = nQ + 3 * nK;
        const bool attn_f32 = ws_size >= attnElems * 4 + bf16Elems * 2;

        char* ws = (char*)d_ws;
        float*  attnF = (float*)ws;
        ushort* attnH = (ushort*)ws;
        ushort* q  = (ushort*)(ws + (attn_f32 ? attnElems * 4 : attnElems * 2));
        ushort* k  = q + nQ;
        ushort* v  = k + nK;
        ushort* vt = v + nK;

        gemm_sync<float, float, ushort><<<dim3(QD / 128, S_LEN / 128), blk, 0, stream>>>(hidden, wq, q, S_LEN, QD, HDIM);
        gemm_sync<float, float, ushort><<<dim3(KD / 128, S_LEN / 128), blk, 0, stream>>>(hidden, wk, k, S_LEN, KD, HDIM);
        gemm_sync<float, float, ushort><<<dim3(KD / 128, S_LEN / 128), blk, 0, stream>>>(hidden, wv, v, S_LEN, KD, HDIM);
        rope_kernel<<<(S_LEN * NHEAD * 128) / 256, blk, 0, stream>>>(q, cosb, sinb, NHEAD);
        rope_kernel<<<(S_LEN * NKVH * 128) / 256, blk, 0, stream>>>(k, cosb, sinb, NKVH);
        vtrans_kernel<<<dim3(S_LEN / 64, KD / 64), blk, 0, stream>>>(v, vt);
        if (attn_f32) {
            attn_kernel<float><<<dim3(S_LEN / 64, NHEAD), blk, 0, stream>>>(q, k, vt, attnF);
            gemm_sync<float, float, float><<<dim3(HDIM / 128, S_LEN / 128), blk, 0, stream>>>(attnF, wo, outp, S_LEN, HDIM, QD);
        } else {
            attn_kernel<ushort><<<dim3(S_LEN / 64, NHEAD), blk, 0, stream>>>(q, k, vt, attnH);
            gemm_sync<ushort, float, float><<<dim3(HDIM / 128, S_LEN / 128), blk, 0, stream>>>(attnH, wo, outp, S_LEN, HDIM, QD);
        }
    }
}

// Round 4
// 652.228 us; speedup vs baseline: 1.6648x; 1.3076x over previous
//
#include <hip/hip_runtime.h>
#include <stdint.h>

// Gemma2 attention (B=1). Global tensors are FLOAT32; MFMA compute is bf16.
#define S_LEN 2048
#define HDIM  3584
#define NHEAD 16
#define NKVH  8
#define DHEAD 256
#define QD    (NHEAD * DHEAD)   // 4096
#define KD    (NKVH * DHEAD)    // 2048
#define QKVD  (QD + 2 * KD)     // 8192
#define WINDOW 1024
#define MASK_VAL (-1e9f)

typedef __bf16 bf16x8 __attribute__((ext_vector_type(8)));
typedef float  f32x4  __attribute__((ext_vector_type(4)));

__device__ __forceinline__ float bf2f(ushort u) {
    union { uint32_t i; float f; } v; v.i = ((uint32_t)u) << 16; return v.f;
}
__device__ __forceinline__ ushort f2bf(float f) {
    union { float f; uint32_t i; } v; v.f = f;
    uint32_t r = (v.i + 0x7FFF + ((v.i >> 16) & 1)) >> 16;  // RNE
    return (ushort)r;
}
__device__ __forceinline__ void gll16(const ushort* g, ushort* l) {
    __builtin_amdgcn_global_load_lds(
        (const __attribute__((address_space(1))) void*)g,
        (__attribute__((address_space(3))) void*)l, 16, 0, 0);
}

// ---------------------------------------------------------------------------
// f32 -> bf16 bulk convert (8 elems/thread).
// ---------------------------------------------------------------------------
__global__ __launch_bounds__(256) void cvt_kernel(const float* __restrict__ src,
                                                  ushort* __restrict__ dst, int n8)
{
    int i = blockIdx.x * blockDim.x + threadIdx.x;
    if (i >= n8) return;
    float4 a = ((const float4*)src)[i * 2];
    float4 b = ((const float4*)src)[i * 2 + 1];
    ushort tmp[8];
    tmp[0] = f2bf(a.x); tmp[1] = f2bf(a.y); tmp[2] = f2bf(a.z); tmp[3] = f2bf(a.w);
    tmp[4] = f2bf(b.x); tmp[5] = f2bf(b.y); tmp[6] = f2bf(b.z); tmp[7] = f2bf(b.w);
    ((uint4*)dst)[i] = *(uint4*)tmp;
}

// ---------------------------------------------------------------------------
// f32 A-tile staging with convert (for the no-hb fallback tier).
// ---------------------------------------------------------------------------
__device__ __forceinline__ void stage_f32(ushort* __restrict__ dst,
                                          const float* __restrict__ src,
                                          int r0, int K, int kt, int t)
{
#pragma unroll
    for (int i = 0; i < 4; i++) {
        int g = t + i * 256;
        int row = g >> 3, c = g & 7;
        float4 f = *(const float4*)(src + (size_t)(r0 + row) * K + kt + c * 4);
        ushort4 u;
        u.x = f2bf(f.x); u.y = f2bf(f.y); u.z = f2bf(f.z); u.w = f2bf(f.w);
        *(ushort4*)(dst + row * 32 + c * 4) = u;
    }
}

// ---------------------------------------------------------------------------
// GEMM: C[M,N] = A[M,K]*B[N,K]^T. B bf16 via global_load_lds; A bf16 (async)
// or f32 (convert-in-staging). 128x128 tile, BK=32, 256 threads.
// ---------------------------------------------------------------------------
template <typename TA, typename TC>
__global__ __launch_bounds__(256) void gemm_async(const TA* __restrict__ A,
                                                  const ushort* __restrict__ B,
                                                  TC* __restrict__ C,
                                                  int M, int N, int K)
{
    __shared__ __align__(16) ushort As[128 * 32];
    __shared__ __align__(16) ushort Bs[128 * 32];

    const int t    = threadIdx.x;
    const int lane = t & 63;
    const int w    = t >> 6;
    const int l15  = lane & 15;
    const int quad = lane >> 4;
    const int m0   = blockIdx.y * 128;
    const int n0   = blockIdx.x * 128;
    const int wm   = (w >> 1) * 64;
    const int wn   = (w & 1) * 64;
    const int srow = lane >> 2;
    const int scol = (lane & 3) * 8;

    f32x4 acc[4][4] = {};

    for (int kt = 0; kt < K; kt += 32) {
        __syncthreads();
#pragma unroll
        for (int j = 0; j < 2; j++) {
            const int rb = w * 32 + j * 16;
            if constexpr (sizeof(TA) == 2) {
                gll16((const ushort*)A + (size_t)(m0 + rb + srow) * K + kt + scol,
                      As + rb * 32);
            }
            gll16(B + (size_t)(n0 + rb + srow) * K + kt + scol, Bs + rb * 32);
        }
        if constexpr (sizeof(TA) == 4)
            stage_f32(As, (const float*)A, m0, K, kt, t);
        __syncthreads();

        bf16x8 a[4], b[4];
#pragma unroll
        for (int mi = 0; mi < 4; mi++)
            a[mi] = *(const bf16x8*)(As + (wm + mi * 16 + l15) * 32 + quad * 8);
#pragma unroll
        for (int ni = 0; ni < 4; ni++)
            b[ni] = *(const bf16x8*)(Bs + (wn + ni * 16 + l15) * 32 + quad * 8);
#pragma unroll
        for (int mi = 0; mi < 4; mi++)
#pragma unroll
            for (int ni = 0; ni < 4; ni++)
                acc[mi][ni] = __builtin_amdgcn_mfma_f32_16x16x32_bf16(
                    a[mi], b[ni], acc[mi][ni], 0, 0, 0);
    }

#pragma unroll
    for (int mi = 0; mi < 4; mi++)
#pragma unroll
        for (int ni = 0; ni < 4; ni++)
#pragma unroll
            for (int r = 0; r < 4; r++) {
                int row = m0 + wm + mi * 16 + quad * 4 + r;
                int col = n0 + wn + ni * 16 + l15;
                float val = acc[mi][ni][r];
                if constexpr (sizeof(TC) == 4) C[(size_t)row * N + col] = val;
                else                           C[(size_t)row * N + col] = f2bf(val);
            }
}

// ---------------------------------------------------------------------------
// Slow-fallback GEMM (f32 A and B, convert-in-staging both).
// ---------------------------------------------------------------------------
__global__ __launch_bounds__(256) void gemm_sync(const float* __restrict__ A,
                                                 const float* __restrict__ B,
                                                 ushort* __restrict__ C,
                                                 int M, int N, int K)
{
    __shared__ __align__(16) ushort As[128 * 32];
    __shared__ __align__(16) ushort Bs[128 * 32];
    const int t = threadIdx.x, lane = t & 63, w = t >> 6;
    const int l15 = lane & 15, quad = lane >> 4;
    const int m0 = blockIdx.y * 128, n0 = blockIdx.x * 128;
    const int wm = (w >> 1) * 64, wn = (w & 1) * 64;
    f32x4 acc[4][4] = {};
    for (int kt = 0; kt < K; kt += 32) {
        __syncthreads();
        stage_f32(As, A, m0, K, kt, t);
        stage_f32(Bs, B, n0, K, kt, t);
        __syncthreads();
        bf16x8 a[4], b[4];
#pragma unroll
        for (int mi = 0; mi < 4; mi++)
            a[mi] = *(const bf16x8*)(As + (wm + mi * 16 + l15) * 32 + quad * 8);
#pragma unroll
        for (int ni = 0; ni < 4; ni++)
            b[ni] = *(const bf16x8*)(Bs + (wn + ni * 16 + l15) * 32 + quad * 8);
#pragma unroll
        for (int mi = 0; mi < 4; mi++)
#pragma unroll
            for (int ni = 0; ni < 4; ni++)
                acc[mi][ni] = __builtin_amdgcn_mfma_f32_16x16x32_bf16(
                    a[mi], b[ni], acc[mi][ni], 0, 0, 0);
    }
#pragma unroll
    for (int mi = 0; mi < 4; mi++)
#pragma unroll
        for (int ni = 0; ni < 4; ni++)
#pragma unroll
            for (int r = 0; r < 4; r++)
                C[(size_t)(m0 + wm + mi * 16 + quad * 4 + r) * N +
                  n0 + wn + ni * 16 + l15] = f2bf(acc[mi][ni][r]);
}

// O-projection variant writing f32 (for fallback path)
__global__ __launch_bounds__(256) void gemm_sync_hf(const ushort* __restrict__ A,
                                                    const float* __restrict__ B,
                                                    float* __restrict__ C,
                                                    int M, int N, int K)
{
    __shared__ __align__(16) ushort As[128 * 32];
    __shared__ __align__(16) ushort Bs[128 * 32];
    const int t = threadIdx.x, lane = t & 63, w = t >> 6;
    const int l15 = lane & 15, quad = lane >> 4;
    const int m0 = blockIdx.y * 128, n0 = blockIdx.x * 128;
    const int wm = (w >> 1) * 64, wn = (w & 1) * 64;
    f32x4 acc[4][4] = {};
    for (int kt = 0; kt < K; kt += 32) {
        __syncthreads();
#pragma unroll
        for (int i = 0; i < 2; i++) {
            int g = t + i * 256;
            int row = g >> 2, c = g & 3;
            *(uint4*)(As + row * 32 + c * 8) =
                *(const uint4*)(A + (size_t)(m0 + row) * K + kt + c * 8);
        }
        stage_f32(Bs, B, n0, K, kt, t);
        __syncthreads();
        bf16x8 a[4], b[4];
#pragma unroll
        for (int mi = 0; mi < 4; mi++)
            a[mi] = *(const bf16x8*)(As + (wm + mi * 16 + l15) * 32 + quad * 8);
#pragma unroll
        for (int ni = 0; ni < 4; ni++)
            b[ni] = *(const bf16x8*)(Bs + (wn + ni * 16 + l15) * 32 + quad * 8);
#pragma unroll
        for (int mi = 0; mi < 4; mi++)
#pragma unroll
            for (int ni = 0; ni < 4; ni++)
                acc[mi][ni] = __builtin_amdgcn_mfma_f32_16x16x32_bf16(
                    a[mi], b[ni], acc[mi][ni], 0, 0, 0);
    }
#pragma unroll
    for (int mi = 0; mi < 4; mi++)
#pragma unroll
        for (int ni = 0; ni < 4; ni++)
#pragma unroll
            for (int r = 0; r < 4; r++)
                C[(size_t)(m0 + wm + mi * 16 + quad * 4 + r) * N +
                  n0 + wn + ni * 16 + l15] = acc[mi][ni][r];
}

// ---------------------------------------------------------------------------
// RoPE in-place on rows of stride `stride`, head count nh at column h*256.
// ---------------------------------------------------------------------------
__global__ void rope_kernel(ushort* __restrict__ x, int stride,
                            const float* __restrict__ cosb,
                            const float* __restrict__ sinb, int nh)
{
    int idx  = blockIdx.x * blockDim.x + threadIdx.x;
    int d    = idx & 127;
    int rest = idx >> 7;
    int h    = rest & (nh - 1);
    int s    = rest / nh;
    size_t base = (size_t)s * stride + h * DHEAD;
    float c  = cosb[s * DHEAD + d];
    float sn = sinb[s * DHEAD + d];
    float x1 = bf2f(x[base + d]);
    float x2 = bf2f(x[base + d + 128]);
    x[base + d]       = f2bf(x1 * c - x2 * sn);
    x[base + d + 128] = f2bf(x2 * c + x1 * sn);
}

// ---------------------------------------------------------------------------
// Transpose V rows (stride `stride`) -> Vt [KD][S_LEN], 64x64 tiles.
// ---------------------------------------------------------------------------
__global__ __launch_bounds__(256) void vtrans_kernel(const ushort* __restrict__ v,
                                                     int stride,
                                                     ushort* __restrict__ vt)
{
    __shared__ __align__(16) ushort tile[64][72];
    int s0 = blockIdx.x * 64, c0 = blockIdx.y * 64;
    int t  = threadIdx.x;
#pragma unroll
    for (int i = 0; i < 2; i++) {
        int cI = t + i * 256;
        int row = cI >> 3, c8 = cI & 7;
        *(uint4*)&tile[row][c8 * 8] =
            *(const uint4*)(v + (size_t)(s0 + row) * stride + c0 + c8 * 8);
    }
    __syncthreads();
#pragma unroll
    for (int i = 0; i < 2; i++) {
        int cI = t + i * 256;
        int crow = cI >> 3, s8 = cI & 7;
        ushort tmp[8];
#pragma unroll
        for (int j = 0; j < 8; j++) tmp[j] = tile[s8 * 8 + j][crow];
        *(uint4*)(vt + (size_t)(c0 + crow) * S_LEN + s0 + s8 * 8) = *(uint4*)tmp;
    }
}

// ---------------------------------------------------------------------------
// Flash attention, block = 64 q-rows x 1 head, 4 waves (16 rows each).
// K and Vt tiles staged via global_load_lds with XOR-swizzled chunks:
// LDS stays linear (hardware requirement); the GLOBAL chunk fetched by lane
// position (row, c) is chunk c ^ (row&7), so fragment reads at
// chunk' = want ^ (row&7) land 2-way-conflict-free on banks.
// ---------------------------------------------------------------------------
template <typename TO>
__global__ __launch_bounds__(256) void attn_kernel(const ushort* __restrict__ qr, int qstride,
                                                   const ushort* __restrict__ kr, int kstride,
                                                   const ushort* __restrict__ vt,
                                                   TO* __restrict__ out)
{
    __shared__ __align__(16) ushort Ks[64 * 256];   // [key][d] 32KB
    __shared__ __align__(16) ushort Vs[256 * 64];   // [d][key] 32KB
    __shared__ __align__(16) ushort Ps[4][16 * 68]; // padded, 8.5KB

    const int t    = threadIdx.x;
    const int lane = t & 63;
    const int w    = t >> 6;
    const int l15  = lane & 15;
    const int quad = lane >> 4;
    const int q0B  = blockIdx.x * 64;
    const int q0   = q0B + w * 16;
    const int h    = blockIdx.y;
    const int kvh  = h >> 1;  // GROUPS = 2

    // Q fragments (one-time)
    bf16x8 aQ[8];
    const ushort* qrow = qr + (size_t)(q0 + l15) * qstride + h * DHEAD;
#pragma unroll
    for (int kk = 0; kk < 8; kk++)
        aQ[kk] = *(const bf16x8*)(qrow + kk * 32 + quad * 8);

    f32x4 oacc[16] = {};
    float m_i[4], l_i[4];
#pragma unroll
    for (int r = 0; r < 4; r++) { m_i[r] = -1e30f; l_i[r] = 0.f; }

    int km = q0B - (WINDOW - 1);
    if (km < 0) km = 0;
    km &= ~63;

    for (int kb = km; kb < q0B + 64; kb += 64) {
        __syncthreads();
        // stage K tile [64][256]: 2048 chunks of 16B, swizzled source
#pragma unroll
        for (int i = 0; i < 8; i++) {
            int base = i * 256 + w * 64;
            int idx  = base + lane;
            int row = idx >> 5, c = idx & 31;
            int cs = c ^ (row & 7);
            gll16(kr + (size_t)(kb + row) * kstride + kvh * DHEAD + cs * 8,
                  Ks + base * 8);
        }
        // stage Vt tile [256][64]: 2048 chunks
#pragma unroll
        for (int i = 0; i < 8; i++) {
            int base = i * 256 + w * 64;
            int idx  = base + lane;
            int row = idx >> 3, c = idx & 7;
            int cs = c ^ (row & 7);
            gll16(vt + (size_t)(kvh * DHEAD + row) * S_LEN + kb + cs * 8,
                  Vs + base * 8);
        }
        __syncthreads();

        // ---- QK^T: S[16q][64k] ----
        f32x4 sc[4] = {};
#pragma unroll
        for (int ni = 0; ni < 4; ni++) {
            int row = ni * 16 + l15;
#pragma unroll
            for (int kk = 0; kk < 8; kk++) {
                int cp = (kk * 4 + quad) ^ (row & 7);
                bf16x8 bk = *(const bf16x8*)(Ks + row * 256 + cp * 8);
                sc[ni] = __builtin_amdgcn_mfma_f32_16x16x32_bf16(aQ[kk], bk, sc[ni], 0, 0, 0);
            }
        }

        // ---- softcap + mask + online softmax ----
        float p[4][4];
        float mt[4] = { -1e30f, -1e30f, -1e30f, -1e30f };
#pragma unroll
        for (int ni = 0; ni < 4; ni++)
#pragma unroll
            for (int r = 0; r < 4; r++) {
                int qi = q0 + quad * 4 + r;
                int ki = kb + ni * 16 + l15;
                float x = sc[ni][r] * 0.0625f;          // SCALING = 1/16
                float e = __expf(x * 0.04f);            // tanh via exp(2x/50)
                x = 50.f * (e - 1.f) / (e + 1.f);
                bool ok = (ki <= qi) && (qi - ki < WINDOW);
                x = ok ? x : MASK_VAL;
                p[ni][r] = x;
                mt[r] = fmaxf(mt[r], x);
            }
#pragma unroll
        for (int r = 0; r < 4; r++)
#pragma unroll
            for (int off = 1; off < 16; off <<= 1)
                mt[r] = fmaxf(mt[r], __shfl_xor(mt[r], off));

        float alpha[4], rs[4];
#pragma unroll
        for (int r = 0; r < 4; r++) {
            float mn = fmaxf(m_i[r], mt[r]);
            alpha[r] = __expf(m_i[r] - mn);
            m_i[r] = mn;
            rs[r] = 0.f;
        }
#pragma unroll
        for (int ni = 0; ni < 4; ni++)
#pragma unroll
            for (int r = 0; r < 4; r++) {
                float pe = __expf(p[ni][r] - m_i[r]);
                rs[r] += pe;
                Ps[w][(quad * 4 + r) * 68 + ni * 16 + l15] = f2bf(pe);
            }
#pragma unroll
        for (int r = 0; r < 4; r++) {
#pragma unroll
            for (int off = 1; off < 16; off <<= 1)
                rs[r] += __shfl_xor(rs[r], off);
            l_i[r] = l_i[r] * alpha[r] + rs[r];
        }
#pragma unroll
        for (int nd = 0; nd < 16; nd++)
#pragma unroll
            for (int r = 0; r < 4; r++)
                oacc[nd][r] *= alpha[r];

        __asm__ volatile("s_waitcnt lgkmcnt(0)" ::: "memory");

        // ---- PV: O[16q][256d] += P[16x64] * V ----
        bf16x8 aP[2];
#pragma unroll
        for (int kk = 0; kk < 2; kk++)
            aP[kk] = *(const bf16x8*)(&Ps[w][l15 * 68 + kk * 32 + quad * 8]);
#pragma unroll
        for (int nd = 0; nd < 16; nd++) {
            int row = nd * 16 + l15;
#pragma unroll
            for (int kk = 0; kk < 2; kk++) {
                int cp = (kk * 4 + quad) ^ (row & 7);
                bf16x8 bv = *(const bf16x8*)(Vs + row * 64 + cp * 8);
                oacc[nd] = __builtin_amdgcn_mfma_f32_16x16x32_bf16(aP[kk], bv, oacc[nd], 0, 0, 0);
            }
        }
    }

#pragma unroll
    for (int nd = 0; nd < 16; nd++)
#pragma unroll
        for (int r = 0; r < 4; r++) {
            int qi = q0 + quad * 4 + r;
            int d  = nd * 16 + l15;
            float val = oacc[nd][r] / l_i[r];
            if constexpr (sizeof(TO) == 4) out[(size_t)qi * QD + h * DHEAD + d] = val;
            else                           out[(size_t)qi * QD + h * DHEAD + d] = f2bf(val);
        }
}

// ---------------------------------------------------------------------------
extern "C" void kernel_launch(void* const* d_in, const int* in_sizes, int n_in,
                              void* d_out, int out_size, void* d_ws, size_t ws_size,
                              hipStream_t stream)
{
    const float* hidden = (const float*)d_in[0];
    const float* cosb   = (const float*)d_in[1];
    const float* sinb   = (const float*)d_in[2];
    const float* wq     = (const float*)d_in[3];
    const float* wk     = (const float*)d_in[4];
    const float* wv     = (const float*)d_in[5];
    const float* wo     = (const float*)d_in[6];
    float* outp = (float*)d_out;

    const size_t nH   = (size_t)S_LEN * HDIM;      //  7,340,032
    const size_t nWQ  = (size_t)QD * HDIM;         // 14,680,064
    const size_t nWK  = (size_t)KD * HDIM;         //  7,340,032
    const size_t nWB  = (size_t)QKVD * HDIM;       // 29,360,128
    const size_t nQKV = (size_t)S_LEN * QKVD;      // 16,777,216
    const size_t nAT  = (size_t)S_LEN * QD;        //  8,388,608
    const size_t nVT  = (size_t)S_LEN * KD;        //  4,194,304

    dim3 blk(256);
    const size_t needA = (nH + nWB + nQKV) * 2;    // ~107 MB (with hb)
    const size_t needB = (nWB + nQKV) * 2;         // ~92 MB  (A stays f32)

    if (ws_size >= needB) {
        const bool haveHb = ws_size >= needA;
        ushort* wb  = (ushort*)d_ws;               // also hosts at/vt/ob later
        ushort* qkv = wb + nWB;
        ushort* hb  = qkv + nQKV;                  // only if haveHb
        ushort* at  = wb;                          // alias (dead after QKV GEMM)
        ushort* vtb = wb + nAT;
        ushort* ob  = wb + nAT + nVT;              // nAT+nVT+nWQ <= nWB  ✓

        // weight converts into wb
        cvt_kernel<<<(int)(nWQ / 8 / 256), blk, 0, stream>>>(wq, wb, (int)(nWQ / 8));
        cvt_kernel<<<(int)(nWK / 8 / 256), blk, 0, stream>>>(wk, wb + nWQ, (int)(nWK / 8));
        cvt_kernel<<<(int)(nWK / 8 / 256), blk, 0, stream>>>(wv, wb + nWQ + nWK, (int)(nWK / 8));

        // fused QKV projection: [2048 x 8192] = hidden * wb^T
        if (haveHb) {
            cvt_kernel<<<(int)(nH / 8 / 256), blk, 0, stream>>>(hidden, hb, (int)(nH / 8));
            gemm_async<ushort, ushort><<<dim3(QKVD / 128, S_LEN / 128), blk, 0, stream>>>(
                hb, wb, qkv, S_LEN, QKVD, HDIM);
        } else {
            gemm_async<float, ushort><<<dim3(QKVD / 128, S_LEN / 128), blk, 0, stream>>>(
                hidden, wb, qkv, S_LEN, QKVD, HDIM);
        }

        // wb region now dead -> reuse for ob / vt / at
        cvt_kernel<<<(int)(nWQ / 8 / 256), blk, 0, stream>>>(wo, ob, (int)(nWQ / 8));

        rope_kernel<<<(S_LEN * NHEAD * 128) / 256, blk, 0, stream>>>(qkv, QKVD, cosb, sinb, NHEAD);
        rope_kernel<<<(S_LEN * NKVH * 128) / 256, blk, 0, stream>>>(qkv + QD, QKVD, cosb, sinb, NKVH);
        vtrans_kernel<<<dim3(S_LEN / 64, KD / 64), blk, 0, stream>>>(qkv + QD + KD, QKVD, vtb);

        attn_kernel<ushort><<<dim3(S_LEN / 64, NHEAD), blk, 0, stream>>>(
            qkv, QKVD, qkv + QD, QKVD, vtb, at);

        gemm_async<ushort, float><<<dim3(HDIM / 128, S_LEN / 128), blk, 0, stream>>>(
            at, ob, outp, S_LEN, HDIM, QD);
    } else {
        // slow fallback: f32 convert-in-staging everywhere
        ushort* q  = (ushort*)d_ws;
        ushort* k  = q + nAT;
        ushort* v  = k + nVT;
        ushort* vtb = v + nVT;
        ushort* at = vtb + nVT;

        gemm_sync<<<dim3(QD / 128, S_LEN / 128), blk, 0, stream>>>(hidden, wq, q, S_LEN, QD, HDIM);
        gemm_sync<<<dim3(KD / 128, S_LEN / 128), blk, 0, stream>>>(hidden, wk, k, S_LEN, KD, HDIM);
        gemm_sync<<<dim3(KD / 128, S_LEN / 128), blk, 0, stream>>>(hidden, wv, v, S_LEN, KD, HDIM);
        rope_kernel<<<(S_LEN * NHEAD * 128) / 256, blk, 0, stream>>>(q, QD, cosb, sinb, NHEAD);
        rope_kernel<<<(S_LEN * NKVH * 128) / 256, blk, 0, stream>>>(k, KD, cosb, sinb, NKVH);
        vtrans_kernel<<<dim3(S_LEN / 64, KD / 64), blk, 0, stream>>>(v, KD, vtb);
        attn_kernel<ushort><<<dim3(S_LEN / 64, NHEAD), blk, 0, stream>>>(q, QD, k, KD, vtb, at);
        gemm_sync_hf<<<dim3(HDIM / 128, S_LEN / 128), blk, 0, stream>>>(at, wo, outp, S_LEN, HDIM, QD);
    }
}

// Round 5
// 622.565 us; speedup vs baseline: 1.7441x; 1.0476x over previous
//
#include <hip/hip_runtime.h>
#include <stdint.h>

// Gemma2 attention (B=1). Global tensors are FLOAT32; MFMA compute is bf16.
#define S_LEN 2048
#define HDIM  3584
#define NHEAD 16
#define NKVH  8
#define DHEAD 256
#define QD    (NHEAD * DHEAD)   // 4096
#define KD    (NKVH * DHEAD)    // 2048
#define QKVD  (QD + 2 * KD)     // 8192
#define WINDOW 1024
#define MASK_VAL (-1e9f)

typedef __bf16 bf16x8 __attribute__((ext_vector_type(8)));
typedef float  f32x4  __attribute__((ext_vector_type(4)));

__device__ __forceinline__ float bf2f(ushort u) {
    union { uint32_t i; float f; } v; v.i = ((uint32_t)u) << 16; return v.f;
}
__device__ __forceinline__ ushort f2bf(float f) {
    union { float f; uint32_t i; } v; v.f = f;
    uint32_t r = (v.i + 0x7FFF + ((v.i >> 16) & 1)) >> 16;  // RNE
    return (ushort)r;
}
__device__ __forceinline__ void gll16(const ushort* g, ushort* l) {
    __builtin_amdgcn_global_load_lds(
        (const __attribute__((address_space(1))) void*)g,
        (__attribute__((address_space(3))) void*)l, 16, 0, 0);
}

// ---------------------------------------------------------------------------
// Fused f32->bf16 convert for hidden + wq + wk + wv + wo (Tier A).
// Segment sizes in 8-element units; 8 elems/thread.
// ---------------------------------------------------------------------------
#define N_H8  (S_LEN * HDIM / 8)       // 917504
#define N_WQ8 (QD * HDIM / 8)          // 1835008
#define N_WK8 (KD * HDIM / 8)          // 917504
#define N_WO8 (HDIM * QD / 8)          // 1835008
#define N_CVT (N_H8 + N_WQ8 + 2 * N_WK8 + N_WO8)

__global__ __launch_bounds__(256) void cvt5_kernel(
    const float* __restrict__ hid, const float* __restrict__ wq,
    const float* __restrict__ wk,  const float* __restrict__ wv,
    const float* __restrict__ wo,
    ushort* __restrict__ hb, ushort* __restrict__ wb, ushort* __restrict__ ob)
{
    int j = blockIdx.x * blockDim.x + threadIdx.x;
    const float* s; ushort* d;
    if (j < N_H8)                { s = hid; d = hb; }
    else if ((j -= N_H8) < N_WQ8)  { s = wq; d = wb; }
    else if ((j -= N_WQ8) < N_WK8) { s = wk; d = wb + (size_t)QD * HDIM; }
    else if ((j -= N_WK8) < N_WK8) { s = wv; d = wb + (size_t)(QD + KD) * HDIM; }
    else                         { j -= N_WK8; s = wo; d = ob; }
    float4 a = ((const float4*)s)[(size_t)j * 2];
    float4 b = ((const float4*)s)[(size_t)j * 2 + 1];
    ushort tmp[8];
    tmp[0] = f2bf(a.x); tmp[1] = f2bf(a.y); tmp[2] = f2bf(a.z); tmp[3] = f2bf(a.w);
    tmp[4] = f2bf(b.x); tmp[5] = f2bf(b.y); tmp[6] = f2bf(b.z); tmp[7] = f2bf(b.w);
    ((uint4*)d)[j] = *(uint4*)tmp;
}

// single-tensor convert (Tier B)
__global__ __launch_bounds__(256) void cvt_kernel(const float* __restrict__ src,
                                                  ushort* __restrict__ dst, int n8)
{
    int i = blockIdx.x * blockDim.x + threadIdx.x;
    if (i >= n8) return;
    float4 a = ((const float4*)src)[i * 2];
    float4 b = ((const float4*)src)[i * 2 + 1];
    ushort tmp[8];
    tmp[0] = f2bf(a.x); tmp[1] = f2bf(a.y); tmp[2] = f2bf(a.z); tmp[3] = f2bf(a.w);
    tmp[4] = f2bf(b.x); tmp[5] = f2bf(b.y); tmp[6] = f2bf(b.z); tmp[7] = f2bf(b.w);
    ((uint4*)dst)[i] = *(uint4*)tmp;
}

// ---------------------------------------------------------------------------
// f32 tile staging with convert, bank-swizzled to match frag reads.
// LDS(row, chunk cl) holds global chunk cl ^ ((row>>1)&3).
// ---------------------------------------------------------------------------
__device__ __forceinline__ void stage_f32(ushort* __restrict__ dst,
                                          const float* __restrict__ src,
                                          int r0, int K, int kt, int t)
{
#pragma unroll
    for (int i = 0; i < 4; i++) {
        int g = t + i * 256;
        int row = g >> 3, c = g & 7;              // c = 4-elem group
        float4 f = *(const float4*)(src + (size_t)(r0 + row) * K + kt + c * 4);
        ushort4 u;
        u.x = f2bf(f.x); u.y = f2bf(f.y); u.z = f2bf(f.z); u.w = f2bf(f.w);
        int cl = (c >> 1) ^ ((row >> 1) & 3);     // swizzled 16B chunk
        *(ushort4*)(dst + row * 32 + cl * 8 + (c & 1) * 4) = u;
    }
}

// ---------------------------------------------------------------------------
// GEMM: C[M,N] = A[M,K]*B[N,K]^T. bf16 via global_load_lds (swizzled source
// so LDS chunk (row,c) holds global chunk c^((row>>1)&3) -> 2-way banks).
// 128x128 tile, BK=32, 256 threads, 2x2 waves of 64x64.
// ---------------------------------------------------------------------------
template <typename TA, typename TC>
__global__ __launch_bounds__(256) void gemm_async(const TA* __restrict__ A,
                                                  const ushort* __restrict__ B,
                                                  TC* __restrict__ C,
                                                  int M, int N, int K)
{
    __shared__ __align__(16) ushort As[128 * 32];
    __shared__ __align__(16) ushort Bs[128 * 32];

    const int t    = threadIdx.x;
    const int lane = t & 63;
    const int w    = t >> 6;
    const int l15  = lane & 15;
    const int quad = lane >> 4;
    const int m0   = blockIdx.y * 128;
    const int n0   = blockIdx.x * 128;
    const int wm   = (w >> 1) * 64;
    const int wn   = (w & 1) * 64;
    const int srow = lane >> 2;                        // staging row in chunk of 16
    const int scol = ((lane & 3) ^ ((srow >> 1) & 3)) * 8;  // swizzled source col
    const int sw   = (l15 >> 1) & 3;                   // frag-read swizzle

    f32x4 acc[4][4] = {};

    for (int kt = 0; kt < K; kt += 32) {
        __syncthreads();
#pragma unroll
        for (int j = 0; j < 2; j++) {
            const int rb = w * 32 + j * 16;
            if constexpr (sizeof(TA) == 2) {
                gll16((const ushort*)A + (size_t)(m0 + rb + srow) * K + kt + scol,
                      As + rb * 32);
            }
            gll16(B + (size_t)(n0 + rb + srow) * K + kt + scol, Bs + rb * 32);
        }
        if constexpr (sizeof(TA) == 4)
            stage_f32(As, (const float*)A, m0, K, kt, t);
        __syncthreads();

        bf16x8 a[4], b[4];
#pragma unroll
        for (int mi = 0; mi < 4; mi++)
            a[mi] = *(const bf16x8*)(As + (wm + mi * 16 + l15) * 32 + (quad ^ sw) * 8);
#pragma unroll
        for (int ni = 0; ni < 4; ni++)
            b[ni] = *(const bf16x8*)(Bs + (wn + ni * 16 + l15) * 32 + (quad ^ sw) * 8);
#pragma unroll
        for (int mi = 0; mi < 4; mi++)
#pragma unroll
            for (int ni = 0; ni < 4; ni++)
                acc[mi][ni] = __builtin_amdgcn_mfma_f32_16x16x32_bf16(
                    a[mi], b[ni], acc[mi][ni], 0, 0, 0);
    }

#pragma unroll
    for (int mi = 0; mi < 4; mi++)
#pragma unroll
        for (int ni = 0; ni < 4; ni++)
#pragma unroll
            for (int r = 0; r < 4; r++) {
                int row = m0 + wm + mi * 16 + quad * 4 + r;
                int col = n0 + wn + ni * 16 + l15;
                float val = acc[mi][ni][r];
                if constexpr (sizeof(TC) == 4) C[(size_t)row * N + col] = val;
                else                           C[(size_t)row * N + col] = f2bf(val);
            }
}

// ---------------------------------------------------------------------------
// Slow-fallback GEMMs (Tier C), swizzle-consistent.
// ---------------------------------------------------------------------------
__global__ __launch_bounds__(256) void gemm_sync(const float* __restrict__ A,
                                                 const float* __restrict__ B,
                                                 ushort* __restrict__ C,
                                                 int M, int N, int K)
{
    __shared__ __align__(16) ushort As[128 * 32];
    __shared__ __align__(16) ushort Bs[128 * 32];
    const int t = threadIdx.x, lane = t & 63, w = t >> 6;
    const int l15 = lane & 15, quad = lane >> 4;
    const int sw = (l15 >> 1) & 3;
    const int m0 = blockIdx.y * 128, n0 = blockIdx.x * 128;
    const int wm = (w >> 1) * 64, wn = (w & 1) * 64;
    f32x4 acc[4][4] = {};
    for (int kt = 0; kt < K; kt += 32) {
        __syncthreads();
        stage_f32(As, A, m0, K, kt, t);
        stage_f32(Bs, B, n0, K, kt, t);
        __syncthreads();
        bf16x8 a[4], b[4];
#pragma unroll
        for (int mi = 0; mi < 4; mi++)
            a[mi] = *(const bf16x8*)(As + (wm + mi * 16 + l15) * 32 + (quad ^ sw) * 8);
#pragma unroll
        for (int ni = 0; ni < 4; ni++)
            b[ni] = *(const bf16x8*)(Bs + (wn + ni * 16 + l15) * 32 + (quad ^ sw) * 8);
#pragma unroll
        for (int mi = 0; mi < 4; mi++)
#pragma unroll
            for (int ni = 0; ni < 4; ni++)
                acc[mi][ni] = __builtin_amdgcn_mfma_f32_16x16x32_bf16(
                    a[mi], b[ni], acc[mi][ni], 0, 0, 0);
    }
#pragma unroll
    for (int mi = 0; mi < 4; mi++)
#pragma unroll
        for (int ni = 0; ni < 4; ni++)
#pragma unroll
            for (int r = 0; r < 4; r++)
                C[(size_t)(m0 + wm + mi * 16 + quad * 4 + r) * N +
                  n0 + wn + ni * 16 + l15] = f2bf(acc[mi][ni][r]);
}

__global__ __launch_bounds__(256) void gemm_sync_hf(const ushort* __restrict__ A,
                                                    const float* __restrict__ B,
                                                    float* __restrict__ C,
                                                    int M, int N, int K)
{
    __shared__ __align__(16) ushort As[128 * 32];
    __shared__ __align__(16) ushort Bs[128 * 32];
    const int t = threadIdx.x, lane = t & 63, w = t >> 6;
    const int l15 = lane & 15, quad = lane >> 4;
    const int sw = (l15 >> 1) & 3;
    const int m0 = blockIdx.y * 128, n0 = blockIdx.x * 128;
    const int wm = (w >> 1) * 64, wn = (w & 1) * 64;
    f32x4 acc[4][4] = {};
    for (int kt = 0; kt < K; kt += 32) {
        __syncthreads();
#pragma unroll
        for (int i = 0; i < 2; i++) {
            int g = t + i * 256;
            int row = g >> 2, c = g & 3;
            int cl = c ^ ((row >> 1) & 3);
            *(uint4*)(As + row * 32 + cl * 8) =
                *(const uint4*)(A + (size_t)(m0 + row) * K + kt + c * 8);
        }
        stage_f32(Bs, B, n0, K, kt, t);
        __syncthreads();
        bf16x8 a[4], b[4];
#pragma unroll
        for (int mi = 0; mi < 4; mi++)
            a[mi] = *(const bf16x8*)(As + (wm + mi * 16 + l15) * 32 + (quad ^ sw) * 8);
#pragma unroll
        for (int ni = 0; ni < 4; ni++)
            b[ni] = *(const bf16x8*)(Bs + (wn + ni * 16 + l15) * 32 + (quad ^ sw) * 8);
#pragma unroll
        for (int mi = 0; mi < 4; mi++)
#pragma unroll
            for (int ni = 0; ni < 4; ni++)
                acc[mi][ni] = __builtin_amdgcn_mfma_f32_16x16x32_bf16(
                    a[mi], b[ni], acc[mi][ni], 0, 0, 0);
    }
#pragma unroll
    for (int mi = 0; mi < 4; mi++)
#pragma unroll
        for (int ni = 0; ni < 4; ni++)
#pragma unroll
            for (int r = 0; r < 4; r++)
                C[(size_t)(m0 + wm + mi * 16 + quad * 4 + r) * N +
                  n0 + wn + ni * 16 + l15] = acc[mi][ni][r];
}

// ---------------------------------------------------------------------------
// RoPE in-place on rows of stride `stride`, nh heads at column h*256.
// ---------------------------------------------------------------------------
__global__ void rope_kernel(ushort* __restrict__ x, int stride,
                            const float* __restrict__ cosb,
                            const float* __restrict__ sinb, int nh)
{
    int idx  = blockIdx.x * blockDim.x + threadIdx.x;
    int d    = idx & 127;
    int rest = idx >> 7;
    int h    = rest & (nh - 1);
    int s    = rest / nh;
    size_t base = (size_t)s * stride + h * DHEAD;
    float c  = cosb[s * DHEAD + d];
    float sn = sinb[s * DHEAD + d];
    float x1 = bf2f(x[base + d]);
    float x2 = bf2f(x[base + d + 128]);
    x[base + d]       = f2bf(x1 * c - x2 * sn);
    x[base + d + 128] = f2bf(x2 * c + x1 * sn);
}

// ---------------------------------------------------------------------------
// Transpose V rows (stride) -> Vt [KD][S_LEN], 64x64 tiles.
// ---------------------------------------------------------------------------
__global__ __launch_bounds__(256) void vtrans_kernel(const ushort* __restrict__ v,
                                                     int stride,
                                                     ushort* __restrict__ vt)
{
    __shared__ __align__(16) ushort tile[64][72];
    int s0 = blockIdx.x * 64, c0 = blockIdx.y * 64;
    int t  = threadIdx.x;
#pragma unroll
    for (int i = 0; i < 2; i++) {
        int cI = t + i * 256;
        int row = cI >> 3, c8 = cI & 7;
        *(uint4*)&tile[row][c8 * 8] =
            *(const uint4*)(v + (size_t)(s0 + row) * stride + c0 + c8 * 8);
    }
    __syncthreads();
#pragma unroll
    for (int i = 0; i < 2; i++) {
        int cI = t + i * 256;
        int crow = cI >> 3, s8 = cI & 7;
        ushort tmp[8];
#pragma unroll
        for (int j = 0; j < 8; j++) tmp[j] = tile[s8 * 8 + j][crow];
        *(uint4*)(vt + (size_t)(c0 + crow) * S_LEN + s0 + s8 * 8) = *(uint4*)tmp;
    }
}

// ---------------------------------------------------------------------------
// Flash attention, block = 64 q-rows x 1 head, 4 waves (16 rows each).
// K/Vt staged via swizzled global_load_lds; interior tiles skip mask math;
// v_rcp instead of f32 divide in the softcap.
// ---------------------------------------------------------------------------
template <typename TO>
__global__ __launch_bounds__(256) void attn_kernel(const ushort* __restrict__ qr, int qstride,
                                                   const ushort* __restrict__ kr, int kstride,
                                                   const ushort* __restrict__ vt,
                                                   TO* __restrict__ out)
{
    __shared__ __align__(16) ushort Ks[64 * 256];   // [key][d] 32KB
    __shared__ __align__(16) ushort Vs[256 * 64];   // [d][key] 32KB
    __shared__ __align__(16) ushort Ps[4][16 * 68]; // padded, 8.5KB

    const int t    = threadIdx.x;
    const int lane = t & 63;
    const int w    = t >> 6;
    const int l15  = lane & 15;
    const int quad = lane >> 4;
    const int q0B  = blockIdx.x * 64;
    const int q0   = q0B + w * 16;
    const int h    = blockIdx.y;
    const int kvh  = h >> 1;  // GROUPS = 2

    bf16x8 aQ[8];
    const ushort* qrow = qr + (size_t)(q0 + l15) * qstride + h * DHEAD;
#pragma unroll
    for (int kk = 0; kk < 8; kk++)
        aQ[kk] = *(const bf16x8*)(qrow + kk * 32 + quad * 8);

    f32x4 oacc[16] = {};
    float m_i[4], l_i[4];
#pragma unroll
    for (int r = 0; r < 4; r++) { m_i[r] = -1e30f; l_i[r] = 0.f; }

    int km = q0B - (WINDOW - 1);
    if (km < 0) km = 0;
    km &= ~63;

    for (int kb = km; kb < q0B + 64; kb += 64) {
        __syncthreads();
#pragma unroll
        for (int i = 0; i < 8; i++) {
            int base = i * 256 + w * 64;
            int idx  = base + lane;
            int row = idx >> 5, c = idx & 31;
            int cs = c ^ (row & 7);
            gll16(kr + (size_t)(kb + row) * kstride + kvh * DHEAD + cs * 8,
                  Ks + base * 8);
        }
#pragma unroll
        for (int i = 0; i < 8; i++) {
            int base = i * 256 + w * 64;
            int idx  = base + lane;
            int row = idx >> 3, c = idx & 7;
            int cs = c ^ (row & 7);
            gll16(vt + (size_t)(kvh * DHEAD + row) * S_LEN + kb + cs * 8,
                  Vs + base * 8);
        }
        __syncthreads();

        // ---- QK^T: S[16q][64k] ----
        f32x4 sc[4] = {};
#pragma unroll
        for (int ni = 0; ni < 4; ni++) {
            int row = ni * 16 + l15;
#pragma unroll
            for (int kk = 0; kk < 8; kk++) {
                int cp = (kk * 4 + quad) ^ (row & 7);
                bf16x8 bk = *(const bf16x8*)(Ks + row * 256 + cp * 8);
                sc[ni] = __builtin_amdgcn_mfma_f32_16x16x32_bf16(aQ[kk], bk, sc[ni], 0, 0, 0);
            }
        }

        // ---- softcap + mask + online softmax ----
        // interior: every (qi,ki) in this wave-tile is allowed -> skip masks
        const bool interior = (kb + 63 <= q0) && (q0 + 15 - kb < WINDOW);
        float p[4][4];
        float mt[4] = { -1e30f, -1e30f, -1e30f, -1e30f };
        if (interior) {
#pragma unroll
            for (int ni = 0; ni < 4; ni++)
#pragma unroll
                for (int r = 0; r < 4; r++) {
                    float e = __expf(sc[ni][r] * 0.0025f);  // exp(2*(s/16)/50)
                    float x = 50.f * (e - 1.f) * __builtin_amdgcn_rcpf(e + 1.f);
                    p[ni][r] = x;
                    mt[r] = fmaxf(mt[r], x);
                }
        } else {
#pragma unroll
            for (int ni = 0; ni < 4; ni++)
#pragma unroll
                for (int r = 0; r < 4; r++) {
                    int qi = q0 + quad * 4 + r;
                    int ki = kb + ni * 16 + l15;
                    float e = __expf(sc[ni][r] * 0.0025f);
                    float x = 50.f * (e - 1.f) * __builtin_amdgcn_rcpf(e + 1.f);
                    bool ok = (ki <= qi) && (qi - ki < WINDOW);
                    x = ok ? x : MASK_VAL;
                    p[ni][r] = x;
                    mt[r] = fmaxf(mt[r], x);
                }
        }
#pragma unroll
        for (int r = 0; r < 4; r++)
#pragma unroll
            for (int off = 1; off < 16; off <<= 1)
                mt[r] = fmaxf(mt[r], __shfl_xor(mt[r], off));

        float alpha[4], rs[4];
#pragma unroll
        for (int r = 0; r < 4; r++) {
            float mn = fmaxf(m_i[r], mt[r]);
            alpha[r] = __expf(m_i[r] - mn);
            m_i[r] = mn;
            rs[r] = 0.f;
        }
#pragma unroll
        for (int ni = 0; ni < 4; ni++)
#pragma unroll
            for (int r = 0; r < 4; r++) {
                float pe = __expf(p[ni][r] - m_i[r]);
                rs[r] += pe;
                Ps[w][(quad * 4 + r) * 68 + ni * 16 + l15] = f2bf(pe);
            }
#pragma unroll
        for (int r = 0; r < 4; r++) {
#pragma unroll
            for (int off = 1; off < 16; off <<= 1)
                rs[r] += __shfl_xor(rs[r], off);
            l_i[r] = l_i[r] * alpha[r] + rs[r];
        }
#pragma unroll
        for (int nd = 0; nd < 16; nd++)
#pragma unroll
            for (int r = 0; r < 4; r++)
                oacc[nd][r] *= alpha[r];

        __asm__ volatile("s_waitcnt lgkmcnt(0)" ::: "memory");

        // ---- PV ----
        bf16x8 aP[2];
#pragma unroll
        for (int kk = 0; kk < 2; kk++)
            aP[kk] = *(const bf16x8*)(&Ps[w][l15 * 68 + kk * 32 + quad * 8]);
#pragma unroll
        for (int nd = 0; nd < 16; nd++) {
            int row = nd * 16 + l15;
#pragma unroll
            for (int kk = 0; kk < 2; kk++) {
                int cp = (kk * 4 + quad) ^ (row & 7);
                bf16x8 bv = *(const bf16x8*)(Vs + row * 64 + cp * 8);
                oacc[nd] = __builtin_amdgcn_mfma_f32_16x16x32_bf16(aP[kk], bv, oacc[nd], 0, 0, 0);
            }
        }
    }

#pragma unroll
    for (int r = 0; r < 4; r++) {
        float invl = __builtin_amdgcn_rcpf(l_i[r]);
#pragma unroll
        for (int nd = 0; nd < 16; nd++) {
            int qi = q0 + quad * 4 + r;
            int d  = nd * 16 + l15;
            float val = oacc[nd][r] * invl;
            if constexpr (sizeof(TO) == 4) out[(size_t)qi * QD + h * DHEAD + d] = val;
            else                           out[(size_t)qi * QD + h * DHEAD + d] = f2bf(val);
        }
    }
}

// ---------------------------------------------------------------------------
extern "C" void kernel_launch(void* const* d_in, const int* in_sizes, int n_in,
                              void* d_out, int out_size, void* d_ws, size_t ws_size,
                              hipStream_t stream)
{
    const float* hidden = (const float*)d_in[0];
    const float* cosb   = (const float*)d_in[1];
    const float* sinb   = (const float*)d_in[2];
    const float* wq     = (const float*)d_in[3];
    const float* wk     = (const float*)d_in[4];
    const float* wv     = (const float*)d_in[5];
    const float* wo     = (const float*)d_in[6];
    float* outp = (float*)d_out;

    const size_t nH   = (size_t)S_LEN * HDIM;
    const size_t nWQ  = (size_t)QD * HDIM;
    const size_t nWK  = (size_t)KD * HDIM;
    const size_t nWB  = (size_t)QKVD * HDIM;
    const size_t nWO  = (size_t)HDIM * QD;
    const size_t nQKV = (size_t)S_LEN * QKVD;
    const size_t nAT  = (size_t)S_LEN * QD;
    const size_t nVT  = (size_t)S_LEN * KD;

    dim3 blk(256);
    const size_t needA = (nWB + nQKV + nH + nWO) * 2;  // ~136 MB (hb + dedicated ob)
    const size_t needB = (nWB + nQKV) * 2;             // ~92 MB

    if (ws_size >= needA) {
        ushort* wb  = (ushort*)d_ws;           // later reused for at/vt
        ushort* qkv = wb + nWB;
        ushort* hb  = qkv + nQKV;
        ushort* ob  = hb + nH;
        ushort* at  = wb;                      // alias (wb dead after QKV GEMM)
        ushort* vtb = wb + nAT;

        cvt5_kernel<<<(N_CVT + 255) / 256, blk, 0, stream>>>(hidden, wq, wk, wv, wo, hb, wb, ob);
        gemm_async<ushort, ushort><<<dim3(QKVD / 128, S_LEN / 128), blk, 0, stream>>>(
            hb, wb, qkv, S_LEN, QKVD, HDIM);
        rope_kernel<<<(S_LEN * NHEAD * 128) / 256, blk, 0, stream>>>(qkv, QKVD, cosb, sinb, NHEAD);
        rope_kernel<<<(S_LEN * NKVH * 128) / 256, blk, 0, stream>>>(qkv + QD, QKVD, cosb, sinb, NKVH);
        vtrans_kernel<<<dim3(S_LEN / 64, KD / 64), blk, 0, stream>>>(qkv + QD + KD, QKVD, vtb);
        attn_kernel<ushort><<<dim3(S_LEN / 64, NHEAD), blk, 0, stream>>>(
            qkv, QKVD, qkv + QD, QKVD, vtb, at);
        gemm_async<ushort, float><<<dim3(HDIM / 128, S_LEN / 128), blk, 0, stream>>>(
            at, ob, outp, S_LEN, HDIM, QD);
    } else if (ws_size >= needB) {
        ushort* wb  = (ushort*)d_ws;
        ushort* qkv = wb + nWB;
        ushort* at  = wb;
        ushort* vtb = wb + nAT;
        ushort* ob  = wb + nAT + nVT;          // fits: nAT+nVT+nWO <= nWB

        cvt_kernel<<<(int)(nWQ / 8 / 256), blk, 0, stream>>>(wq, wb, (int)(nWQ / 8));
        cvt_kernel<<<(int)(nWK / 8 / 256), blk, 0, stream>>>(wk, wb + nWQ, (int)(nWK / 8));
        cvt_kernel<<<(int)(nWK / 8 / 256), blk, 0, stream>>>(wv, wb + nWQ + nWK, (int)(nWK / 8));
        gemm_async<float, ushort><<<dim3(QKVD / 128, S_LEN / 128), blk, 0, stream>>>(
            hidden, wb, qkv, S_LEN, QKVD, HDIM);
        cvt_kernel<<<(int)(nWO / 8 / 256), blk, 0, stream>>>(wo, ob, (int)(nWO / 8));
        rope_kernel<<<(S_LEN * NHEAD * 128) / 256, blk, 0, stream>>>(qkv, QKVD, cosb, sinb, NHEAD);
        rope_kernel<<<(S_LEN * NKVH * 128) / 256, blk, 0, stream>>>(qkv + QD, QKVD, cosb, sinb, NKVH);
        vtrans_kernel<<<dim3(S_LEN / 64, KD / 64), blk, 0, stream>>>(qkv + QD + KD, QKVD, vtb);
        attn_kernel<ushort><<<dim3(S_LEN / 64, NHEAD), blk, 0, stream>>>(
            qkv, QKVD, qkv + QD, QKVD, vtb, at);
        gemm_async<ushort, float><<<dim3(HDIM / 128, S_LEN / 128), blk, 0, stream>>>(
            at, ob, outp, S_LEN, HDIM, QD);
    } else {
        ushort* q   = (ushort*)d_ws;
        ushort* k   = q + nAT;
        ushort* v   = k + nVT;
        ushort* vtb = v + nVT;
        ushort* at  = vtb + nVT;

        gemm_sync<<<dim3(QD / 128, S_LEN / 128), blk, 0, stream>>>(hidden, wq, q, S_LEN, QD, HDIM);
        gemm_sync<<<dim3(KD / 128, S_LEN / 128), blk, 0, stream>>>(hidden, wk, k, S_LEN, KD, HDIM);
        gemm_sync<<<dim3(KD / 128, S_LEN / 128), blk, 0, stream>>>(hidden, wv, v, S_LEN, KD, HDIM);
        rope_kernel<<<(S_LEN * NHEAD * 128) / 256, blk, 0, stream>>>(q, QD, cosb, sinb, NHEAD);
        rope_kernel<<<(S_LEN * NKVH * 128) / 256, blk, 0, stream>>>(k, KD, cosb, sinb, NKVH);
        vtrans_kernel<<<dim3(S_LEN / 64, KD / 64), blk, 0, stream>>>(v, KD, vtb);
        attn_kernel<ushort><<<dim3(S_LEN / 64, NHEAD), blk, 0, stream>>>(q, QD, k, KD, vtb, at);
        gemm_sync_hf<<<dim3(HDIM / 128, S_LEN / 128), blk, 0, stream>>>(at, wo, outp, S_LEN, HDIM, QD);
    }
}